// Round 12
// baseline (666.271 us; speedup 1.0000x reference)
//
#include <hip/hip_runtime.h>
#include <hip/hip_bf16.h>

// Problem constants
#define TT 16
#define MM 1024
#define HDIM 128
#define NHEADS 4
#define NROWS (TT*MM)          // 16384
#define MAXDEG 64

typedef __bf16 bf16x8 __attribute__((ext_vector_type(8)));
typedef float f32x4 __attribute__((ext_vector_type(4)));

__device__ __forceinline__ unsigned short f2b(float x) {   // fp32 -> bf16 RNE
    unsigned u = __float_as_uint(x);
    u += 0x7fff + ((u >> 16) & 1);
    return (unsigned short)(u >> 16);
}
__device__ __forceinline__ float bu2f(unsigned short u) {
    return __uint_as_float(((unsigned)u) << 16);
}
__device__ __forceinline__ void unpk8(uint4 v, float* f) {
    f[0] = bu2f((unsigned short)(v.x & 0xffff)); f[1] = bu2f((unsigned short)(v.x >> 16));
    f[2] = bu2f((unsigned short)(v.y & 0xffff)); f[3] = bu2f((unsigned short)(v.y >> 16));
    f[4] = bu2f((unsigned short)(v.z & 0xffff)); f[5] = bu2f((unsigned short)(v.z >> 16));
    f[6] = bu2f((unsigned short)(v.w & 0xffff)); f[7] = bu2f((unsigned short)(v.w >> 16));
}

// ---------------- mask + neighbor-list build ----------------
__global__ __launch_bounds__(256) void k_init(const int* __restrict__ ego,
                                              float* __restrict__ mfl,
                                              int* __restrict__ cnt) {
    int idx = blockIdx.x * 256 + threadIdx.x;   // < 16384
    int t = idx >> 10, i = idx & 1023;
    int b = i >> 8, n = i & 255;
    mfl[idx] = ego[b * (TT * 256) + t * 256 + n] ? 1.f : 0.f;
    cnt[idx] = 0;
}

// 1024 blocks: t(16) x jc(64); thread covers 4 i via float4; 16 j-rows/block.
__global__ __launch_bounds__(256) void k_edges(const float* __restrict__ adj,
                                               const float* __restrict__ mfl,
                                               int* __restrict__ cnt,
                                               int* __restrict__ nbr) {
    int bid = blockIdx.x;
    int t = bid >> 6, jc = bid & 63;
    int tid = threadIdx.x;
    int i0 = tid * 4;
    int rowb = t * MM;
    float mi[4];
#pragma unroll
    for (int r = 0; r < 4; ++r) mi[r] = mfl[rowb + i0 + r];
    __shared__ float ms[16];
    if (tid < 16) ms[tid] = mfl[rowb + jc * 16 + tid];
    __syncthreads();
    const float* at = adj + (size_t)t * MM * MM;
#pragma unroll 4
    for (int jj = 0; jj < 16; ++jj) {
        int j = jc * 16 + jj;
        float4 a = *(const float4*)(at + (size_t)j * MM + i0);
        float mj = ms[jj];
#pragma unroll
        for (int r = 0; r < 4; ++r) {
            int i = i0 + r;
            bool e;
            if (j == i) e = (mi[r] != 0.f);                       // self-loop
            else e = ((&a.x)[r] != 0.f) && (mj != 0.f) && (mi[r] != 0.f);
            if (e) {
                int row = rowb + i;
                int pos = atomicAdd(&cnt[row], 1);
                if (pos < MAXDEG) nbr[(size_t)row * MAXDEG + pos] = j;
            }
        }
    }
}

// ---------------- weight prep: fp32 -> bf16 MFMA B-fragment order ----------------
__global__ __launch_bounds__(256) void k_prep(const float* __restrict__ Wqkv,
                                              const float* __restrict__ Wo,
                                              const float* __restrict__ Wff1,
                                              const float* __restrict__ Wff2,
                                              const float* __restrict__ gW,
                                              unsigned short* __restrict__ Wb) {
    int o = blockIdx.x * 256 + threadIdx.x;     // frag-unit (8 elems) index, < 163840
    const float* src; int cs;
    if (o < 122880) {
        int l = o / 24576, r = o % 24576;
        if (r < 6144) {                 // QKV
            int nt = r >> 8, rem = r & 255, ks = rem >> 6, lane = rem & 63;
            int mt = nt >> 3, cc = nt & 7;
            int k = ks * 32 + ((lane >> 4) << 3), c = cc * 16 + (lane & 15);
            src = Wqkv + ((size_t)(l * 3 + mt) * 128 + k) * 128 + c; cs = 128;
        } else if (r < 8192) {          // Wo
            int u = r - 6144, nt = u >> 8, rem = u & 255, ks = rem >> 6, lane = rem & 63;
            int k = ks * 32 + ((lane >> 4) << 3), c = nt * 16 + (lane & 15);
            src = Wo + (size_t)l * 16384 + (size_t)k * 128 + c; cs = 128;
        } else if (r < 16384) {         // FF1
            int u = r - 8192, nt = u >> 8, rem = u & 255, ks = rem >> 6, lane = rem & 63;
            int k = ks * 32 + ((lane >> 4) << 3), c = nt * 16 + (lane & 15);
            src = Wff1 + (size_t)l * 65536 + (size_t)k * 512 + c; cs = 512;
        } else {                        // FF2
            int u = r - 16384, nt = u >> 10, rem = u & 1023, ks = rem >> 6, lane = rem & 63;
            int k = ks * 32 + ((lane >> 4) << 3), c = nt * 16 + (lane & 15);
            src = Wff2 + (size_t)l * 65536 + (size_t)k * 128 + c; cs = 128;
        }
    } else {                            // GAT gW
        int u = o - 122880;
        int l = u >> 13, rr = u & 8191;
        int nt = rr >> 8, rem = rr & 255, ks = rem >> 6, lane = rem & 63;
        int k = ks * 32 + ((lane >> 4) << 3), c = nt * 16 + (lane & 15);
        src = gW + (size_t)l * 65536 + (size_t)k * 512 + c; cs = 512;
    }
    unsigned v[4];
#pragma unroll
    for (int j = 0; j < 4; ++j)
        v[j] = (unsigned)f2b(src[(2 * j) * (size_t)cs]) |
               ((unsigned)f2b(src[(2 * j + 1) * (size_t)cs]) << 16);
    *(uint4*)(Wb + (size_t)o * 8) = make_uint4(v[0], v[1], v[2], v[3]);
}

// ---------------- GAT layer 1: projection (F=2) + fused ss/sd; h -> bf16 ----------------
__global__ __launch_bounds__(128) void k_gat1(const float* __restrict__ x,
                                              const float* __restrict__ W,
                                              const float* __restrict__ asrc,
                                              const float* __restrict__ adst,
                                              unsigned short* __restrict__ h16,
                                              float* __restrict__ ss,
                                              float* __restrict__ sd) {
    int bid = blockIdx.x;
    int row = ((bid & 7) << 11) + (bid >> 3);   // XCD-locality swizzle
    int tid = threadIdx.x;
    float x0 = x[row * 2], x1 = x[row * 2 + 1];
    float s4[4], d4[4];
#pragma unroll
    for (int hh = 0; hh < 4; ++hh) {
        int o = hh * 128 + tid;
        float v = x0 * W[o] + x1 * W[512 + o];
        h16[(size_t)row * 512 + o] = f2b(v);
        s4[hh] = v * asrc[o];
        d4[hh] = v * adst[o];
    }
#pragma unroll
    for (int hh = 0; hh < 4; ++hh)
        for (int off = 32; off; off >>= 1) {
            s4[hh] += __shfl_down(s4[hh], off, 64);
            d4[hh] += __shfl_down(d4[hh], off, 64);
        }
    __shared__ float red[2][2][4];
    if ((tid & 63) == 0) {
        int w = tid >> 6;
#pragma unroll
        for (int hh = 0; hh < 4; ++hh) { red[w][0][hh] = s4[hh]; red[w][1][hh] = d4[hh]; }
    }
    __syncthreads();
    if (tid < 4) ss[row * 4 + tid] = red[0][0][tid] + red[1][0][tid];
    else if (tid < 8) sd[row * 4 + tid - 4] = red[0][1][tid - 4] + red[1][1][tid - 4];
}

// ---------------- GAT layers 2-6: MFMA projection + fused ss/sd ----------------
__global__ __launch_bounds__(256) void k_gat_h(const unsigned short* __restrict__ x16,
                                               const unsigned short* __restrict__ Wg,
                                               const float* __restrict__ asrc,
                                               const float* __restrict__ adst,
                                               unsigned short* __restrict__ h16,
                                               float* __restrict__ ss,
                                               float* __restrict__ sd) {
    __shared__ __align__(16) unsigned short xb[16 * 136];
    int bid = blockIdx.x;
    int row0 = (((bid & 7) << 7) + (bid >> 3)) * 16;   // band swizzle, XCD mapping
    int tid = threadIdx.x;
    {
        int rr = tid >> 4, cc = (tid & 15) * 8;
        *(uint4*)(xb + rr * 136 + cc) = *(const uint4*)(x16 + (size_t)(row0 + rr) * 128 + cc);
    }
    __syncthreads();
    const int lane = tid & 63, w = tid >> 6;
    const int mrow = lane & 15, quad = lane >> 4;
    bf16x8 af[4];
#pragma unroll
    for (int ks = 0; ks < 4; ++ks)
        af[ks] = *(const bf16x8*)(xb + mrow * 136 + ks * 32 + quad * 8);
    f32x4 acc[8];
#pragma unroll
    for (int i = 0; i < 8; ++i) acc[i] = (f32x4){0.f, 0.f, 0.f, 0.f};
#pragma unroll
    for (int ib = 0; ib < 4; ++ib) {   // batches of 2 nt x 4 ks -> 8 loads in flight
        bf16x8 wb[8];
#pragma unroll
        for (int u = 0; u < 2; ++u) {
            int nt = w * 8 + ib * 2 + u;
#pragma unroll
            for (int ks = 0; ks < 4; ++ks)
                wb[u * 4 + ks] = *(const bf16x8*)(Wg + (size_t)((nt * 4 + ks) * 64 + lane) * 8);
        }
#pragma unroll
        for (int u = 0; u < 2; ++u)
#pragma unroll
            for (int ks = 0; ks < 4; ++ks)
                acc[ib * 2 + u] = __builtin_amdgcn_mfma_f32_16x16x32_bf16(af[ks], wb[u * 4 + ks], acc[ib * 2 + u], 0, 0, 0);
    }
    float ps[4] = {0, 0, 0, 0}, pd[4] = {0, 0, 0, 0};
#pragma unroll
    for (int i = 0; i < 8; ++i) {
        int nt = w * 8 + i, col = nt * 16 + mrow;
        float as_ = asrc[col], ad_ = adst[col];
#pragma unroll
        for (int r = 0; r < 4; ++r) {
            float v = acc[i][r];
            h16[(size_t)(row0 + quad * 4 + r) * 512 + col] = f2b(v);
            ps[r] += v * as_; pd[r] += v * ad_;
        }
    }
#pragma unroll
    for (int off = 1; off < 16; off <<= 1)
#pragma unroll
        for (int r = 0; r < 4; ++r) {
            ps[r] += __shfl_xor(ps[r], off, 64);
            pd[r] += __shfl_xor(pd[r], off, 64);
        }
    if (mrow == 0) {
#pragma unroll
        for (int r = 0; r < 4; ++r) {
            int row = row0 + quad * 4 + r;
            ss[row * 4 + w] = ps[r];
            sd[row * 4 + w] = pd[r];
        }
    }
}

// -------- GAT aggregation: 256 thr, split-neighbor gather (half the serial chain) --------
__global__ __launch_bounds__(256) void k_agg(const unsigned short* __restrict__ h16,
                                             const float* __restrict__ ss,
                                             const float* __restrict__ sd,
                                             const int* __restrict__ cnt,
                                             const int* __restrict__ nbr,
                                             const float* __restrict__ mfl,
                                             const float* __restrict__ bias,
                                             unsigned short* __restrict__ xo16) {
    int bid = blockIdx.x;
    int row = ((bid & 7) << 11) + (bid >> 3);   // same-t rows colocate per XCD
    int tid = threadIdx.x;
    int t = row >> 10;
    if (mfl[row] == 0.f) { if (tid < 128) xo16[(size_t)row * 128 + tid] = 0; return; }
    int c = cnt[row]; if (c > MAXDEG) c = MAXDEG;
    __shared__ int nb[MAXDEG];
    __shared__ float al[MAXDEG][4];
    __shared__ __align__(16) float part[1024];
    if (tid < c) nb[tid] = nbr[(size_t)row * MAXDEG + tid];
    __syncthreads();
    for (int idx = tid; idx < c * 4; idx += 256) {
        int n = idx >> 2, hh = idx & 3, j = nb[n];
        float lg = sd[row * 4 + hh] + ss[(t * MM + j) * 4 + hh];
        al[n][hh] = lg > 0.f ? lg : 0.2f * lg;   // leaky_relu 0.2
    }
    __syncthreads();
    // parallel segment softmax: 32 lanes per head (threads 0-127)
    if (tid < 128) {
        int hh = tid >> 5, n0 = tid & 31;
        float v1 = (n0 < c) ? al[n0][hh] : -1e30f;
        float v2 = (n0 + 32 < c) ? al[n0 + 32][hh] : -1e30f;
        float mx = fmaxf(v1, v2);
#pragma unroll
        for (int off = 16; off; off >>= 1) mx = fmaxf(mx, __shfl_xor(mx, off, 32));
        float e1 = (n0 < c) ? __expf(v1 - mx) : 0.f;
        float e2 = (n0 + 32 < c) ? __expf(v2 - mx) : 0.f;
        float s = e1 + e2;
#pragma unroll
        for (int off = 16; off; off >>= 1) s += __shfl_xor(s, off, 32);
        float inv = 1.f / s;
        if (n0 < c) al[n0][hh] = e1 * inv;
        if (n0 + 32 < c) al[n0 + 32][hh] = e2 * inv;
    }
    __syncthreads();
    // gather: half=tid>>7 handles n = half, half+2, ...; thread owns 4 cols (uint2)
    {
        int half = tid >> 7, ct = tid & 127;
        int hh2 = ct >> 5;
        float a0 = 0.f, a1 = 0.f, a2 = 0.f, a3 = 0.f;
        const unsigned short* hbase = h16 + (size_t)t * MM * 512 + ct * 4;
#pragma unroll 2
        for (int n = half; n < c; n += 2) {
            int j = nb[n];
            uint2 v = *(const uint2*)(hbase + (size_t)j * 512);
            float w = al[n][hh2];
            a0 += w * bu2f((unsigned short)(v.x & 0xffff));
            a1 += w * bu2f((unsigned short)(v.x >> 16));
            a2 += w * bu2f((unsigned short)(v.y & 0xffff));
            a3 += w * bu2f((unsigned short)(v.y >> 16));
        }
        *(float4*)(part + tid * 4) = make_float4(a0, a1, a2, a3);
    }
    __syncthreads();
    if (tid < 128) {
        float v = 0.25f * ((part[tid] + part[512 + tid]) + (part[128 + tid] + part[640 + tid]) +
                           (part[256 + tid] + part[768 + tid]) + (part[384 + tid] + part[896 + tid]))
                + bias[tid];
        xo16[(size_t)row * 128 + tid] = f2b(fmaxf(v, 0.f));
    }
}

// ---------------- in-place LayerNorm, 16 rows x 128, 256 threads ----------------
__device__ __forceinline__ void ln256(float* xs, const float* s, const float* b) {
    int tid = threadIdx.x, row = tid >> 4, lane = tid & 15;
    float* xr = xs + row * 128;
    float sum = 0.f;
#pragma unroll
    for (int k2 = 0; k2 < 8; ++k2) sum += xr[lane + 16 * k2];
#pragma unroll
    for (int off = 8; off; off >>= 1) sum += __shfl_xor(sum, off, 16);
    float mean = sum * (1.f / 128.f);
    float vs = 0.f;
#pragma unroll
    for (int k2 = 0; k2 < 8; ++k2) { float d = xr[lane + 16 * k2] - mean; vs += d * d; }
#pragma unroll
    for (int off = 8; off; off >>= 1) vs += __shfl_xor(vs, off, 16);
    float rstd = rsqrtf(vs * (1.f / 128.f) + 1e-5f);
#pragma unroll
    for (int k2 = 0; k2 < 8; ++k2) {
        int d = lane + 16 * k2;
        float v = (xr[d] - mean) * rstd;
        xr[d] = v * s[d] + b[d];
    }
    __syncthreads();
}

// ------- 5-layer transformer: 1 seq/block, bf16 Q/K/V in LDS, batched MFMA loads --------
// LDS = 2048(xs) + 1024(sb) + 4x1088(xb16,Q,K,V) + hid overlay = 8320 fl = 33280 B
// -> 4 blocks/CU, grid 1024 single pass, 16 waves/CU.
__global__ __launch_bounds__(256, 4) void k_tf(const unsigned short* __restrict__ xg,
        const unsigned short* __restrict__ Wb,
        const float* __restrict__ bqkv, const float* __restrict__ bo,
        const float* __restrict__ ln1s, const float* __restrict__ ln1b,
        const float* __restrict__ ln2s, const float* __restrict__ ln2b,
        const float* __restrict__ bff1, const float* __restrict__ bff2,
        float* __restrict__ out) {
    __shared__ __align__(16) float smem[8320];
    float* xs = smem;                                       // [16][128] fp32 residual
    float* sb = smem + 2048;                                // [16tk][64] fp32 scores
    unsigned short* xb16  = (unsigned short*)(smem + 3072); // [16][136] bf16 A-operand
    unsigned short* Qb16  = (unsigned short*)(smem + 4160); // [16][136]
    unsigned short* Kb16  = (unsigned short*)(smem + 5248); // [16][136]
    unsigned short* Vb16  = (unsigned short*)(smem + 6336); // [16][136]
    unsigned short* hid16 = (unsigned short*)(smem + 4160); // [16][520], overlays Q/K/V
    const int m = blockIdx.x, tid = threadIdx.x;
    const int lane = tid & 63, w = tid >> 6;
    const int mrow = lane & 15, quad = lane >> 4;

    // load + sinusoidal PE
    for (int idx = tid; idx < 2048; idx += 256) {
        int t = idx >> 7, d = idx & 127, jj = d >> 1;
        float arg = (float)t * expf(-(float)(2 * jj) * (9.210340371976184f / 128.f));
        float pe = (d & 1) ? cosf(arg) : sinf(arg);
        xs[idx] = bu2f(xg[(size_t)t * (MM * HDIM) + (size_t)m * HDIM + d]) + pe;
    }
    __syncthreads();

    const int crow = tid >> 4, ccb = (tid & 15) * 8;   // xs->xb16 conversion slots
    for (int l = 0; l < 5; ++l) {
        const unsigned short* Wl = Wb + (size_t)l * 196608;
        // ---- xs -> xb16 ----
        {
            const float* xp = xs + crow * 128 + ccb;
            unsigned v[4];
#pragma unroll
            for (int j = 0; j < 4; ++j)
                v[j] = (unsigned)f2b(xp[2 * j]) | ((unsigned)f2b(xp[2 * j + 1]) << 16);
            *(uint4*)(xb16 + crow * 136 + ccb) = make_uint4(v[0], v[1], v[2], v[3]);
        }
        __syncthreads();
        // ---- QKV via MFMA: wave w does nt = 6w..6w+5, batched loads; Q/K/V -> bf16 ----
        {
            bf16x8 af[4];
#pragma unroll
            for (int ks = 0; ks < 4; ++ks)
                af[ks] = *(const bf16x8*)(xb16 + mrow * 136 + ks * 32 + quad * 8);
            f32x4 acc[6];
#pragma unroll
            for (int i = 0; i < 6; ++i) acc[i] = (f32x4){0.f, 0.f, 0.f, 0.f};
#pragma unroll
            for (int ib = 0; ib < 3; ++ib) {
                bf16x8 wb[8];
#pragma unroll
                for (int u = 0; u < 2; ++u) {
                    int nt = w * 6 + ib * 2 + u;
                    const unsigned short* bp = Wl + (size_t)(nt * 4) * 512 + lane * 8;
#pragma unroll
                    for (int ks = 0; ks < 4; ++ks)
                        wb[u * 4 + ks] = *(const bf16x8*)(bp + ks * 512);
                }
#pragma unroll
                for (int u = 0; u < 2; ++u)
#pragma unroll
                    for (int ks = 0; ks < 4; ++ks)
                        acc[ib * 2 + u] = __builtin_amdgcn_mfma_f32_16x16x32_bf16(af[ks], wb[u * 4 + ks], acc[ib * 2 + u], 0, 0, 0);
            }
#pragma unroll
            for (int i = 0; i < 6; ++i) {
                int nt = w * 6 + i, mt = nt >> 3, cc = nt & 7;
                int col = cc * 16 + mrow;
                float bb = bqkv[l * 384 + mt * 128 + col];
                unsigned short* dst = (mt == 0) ? Qb16 : (mt == 1) ? Kb16 : Vb16;
#pragma unroll
                for (int r = 0; r < 4; ++r)
                    dst[(quad * 4 + r) * 136 + col] = f2b(acc[i][r] + bb);
            }
        }
        __syncthreads();
        // ---- scores (fp32 VALU, bf16 Q/K): thread = (hh, tq, tk0..tk0+3) ----
        {
            int hh = tid >> 6, tq = (tid >> 2) & 15, tk0 = (tid & 3) * 4;
            const unsigned short* qp = Qb16 + tq * 136 + hh * 32;
            float a[4] = {0.f, 0.f, 0.f, 0.f};
#pragma unroll
            for (int d4 = 0; d4 < 4; ++d4) {
                uint4 qv = *(const uint4*)(qp + d4 * 8);
                float qf[8]; unpk8(qv, qf);
#pragma unroll
                for (int j = 0; j < 4; ++j) {
                    uint4 kv = *(const uint4*)(Kb16 + (tk0 + j) * 136 + hh * 32 + d4 * 8);
                    float kf[8]; unpk8(kv, kf);
#pragma unroll
                    for (int e = 0; e < 8; ++e) a[j] += qf[e] * kf[e];
                }
            }
#pragma unroll
            for (int j = 0; j < 4; ++j)
                sb[(tk0 + j) * 64 + hh * 16 + tq] = a[j] * 0.17677669529663687f;
        }
        __syncthreads();
        if (tid < 64) {   // softmax per (hh,tq) column
            float mx = -1e30f;
#pragma unroll
            for (int u = 0; u < 16; ++u) mx = fmaxf(mx, sb[u * 64 + tid]);
            float s = 0.f;
#pragma unroll
            for (int u = 0; u < 16; ++u) { float e = __expf(sb[u * 64 + tid] - mx); sb[u * 64 + tid] = e; s += e; }
            float inv = 1.f / s;
#pragma unroll
            for (int u = 0; u < 16; ++u) sb[u * 64 + tid] *= inv;
        }
        __syncthreads();
        // ---- O = P @ V (fp32, bf16 V) -> xb16 ----
        {
            int o = tid & 127, r0p = (tid >> 7) * 8, hh = o >> 5;
            float accp[8] = {0, 0, 0, 0, 0, 0, 0, 0};
            for (int u = 0; u < 16; ++u) {
                float vv = bu2f(Vb16[u * 136 + o]);
                const float* pp = sb + u * 64 + hh * 16 + r0p;
#pragma unroll
                for (int r = 0; r < 8; ++r) accp[r] += pp[r] * vv;
            }
#pragma unroll
            for (int r = 0; r < 8; ++r)
                xb16[(r0p + r) * 136 + o] = f2b(accp[r]);
        }
        __syncthreads();
        // ---- Wo via MFMA: wave w does nt = 2w, 2w+1; one batch of 8 loads ----
        {
            bf16x8 af[4];
#pragma unroll
            for (int ks = 0; ks < 4; ++ks)
                af[ks] = *(const bf16x8*)(xb16 + mrow * 136 + ks * 32 + quad * 8);
            const unsigned short* Ws = Wl + 49152;
            bf16x8 wb[8];
#pragma unroll
            for (int u = 0; u < 2; ++u) {
                int nt = w * 2 + u;
#pragma unroll
                for (int ks = 0; ks < 4; ++ks)
                    wb[u * 4 + ks] = *(const bf16x8*)(Ws + (size_t)((nt * 4 + ks) * 64 + lane) * 8);
            }
            f32x4 acc[2];
            acc[0] = (f32x4){0.f, 0.f, 0.f, 0.f};
            acc[1] = (f32x4){0.f, 0.f, 0.f, 0.f};
#pragma unroll
            for (int u = 0; u < 2; ++u)
#pragma unroll
                for (int ks = 0; ks < 4; ++ks)
                    acc[u] = __builtin_amdgcn_mfma_f32_16x16x32_bf16(af[ks], wb[u * 4 + ks], acc[u], 0, 0, 0);
#pragma unroll
            for (int u = 0; u < 2; ++u) {
                int col = (w * 2 + u) * 16 + mrow;
                float bb = bo[l * 128 + col];
#pragma unroll
                for (int r = 0; r < 4; ++r)
                    xs[(quad * 4 + r) * 128 + col] += acc[u][r] + bb;
            }
        }
        __syncthreads();
        ln256(xs, ln1s + l * 128, ln1b + l * 128);
        // ---- xs -> xb16 (post-LN1) ----
        {
            const float* xp = xs + crow * 128 + ccb;
            unsigned v[4];
#pragma unroll
            for (int j = 0; j < 4; ++j)
                v[j] = (unsigned)f2b(xp[2 * j]) | ((unsigned)f2b(xp[2 * j + 1]) << 16);
            *(uint4*)(xb16 + crow * 136 + ccb) = make_uint4(v[0], v[1], v[2], v[3]);
        }
        __syncthreads();
        // ---- FF1 via MFMA: wave w does nt = 8w..8w+7, batched; relu -> hid16 ----
        {
            bf16x8 af[4];
#pragma unroll
            for (int ks = 0; ks < 4; ++ks)
                af[ks] = *(const bf16x8*)(xb16 + mrow * 136 + ks * 32 + quad * 8);
            f32x4 acc[8];
#pragma unroll
            for (int i = 0; i < 8; ++i) acc[i] = (f32x4){0.f, 0.f, 0.f, 0.f};
            const unsigned short* Ws = Wl + 65536;
#pragma unroll
            for (int ib = 0; ib < 4; ++ib) {
                bf16x8 wb[8];
#pragma unroll
                for (int u = 0; u < 2; ++u) {
                    int nt = w * 8 + ib * 2 + u;
#pragma unroll
                    for (int ks = 0; ks < 4; ++ks)
                        wb[u * 4 + ks] = *(const bf16x8*)(Ws + (size_t)((nt * 4 + ks) * 64 + lane) * 8);
                }
#pragma unroll
                for (int u = 0; u < 2; ++u)
#pragma unroll
                    for (int ks = 0; ks < 4; ++ks)
                        acc[ib * 2 + u] = __builtin_amdgcn_mfma_f32_16x16x32_bf16(af[ks], wb[u * 4 + ks], acc[ib * 2 + u], 0, 0, 0);
            }
#pragma unroll
            for (int i = 0; i < 8; ++i) {
                int col = (w * 8 + i) * 16 + mrow;
                float bb = bff1[l * 512 + col];
#pragma unroll
                for (int r = 0; r < 4; ++r) {
                    float v = fmaxf(acc[i][r] + bb, 0.f);
                    hid16[(quad * 4 + r) * 520 + col] = f2b(v);
                }
            }
        }
        __syncthreads();
        // ---- FF2 via MFMA: 2 nt x 16 ks per wave, batched 4 ks at a time ----
        {
            f32x4 a0 = (f32x4){0.f, 0.f, 0.f, 0.f};
            f32x4 a1 = (f32x4){0.f, 0.f, 0.f, 0.f};
            const unsigned short* Ws = Wl + 131072;
            int nt0 = w * 2, nt1 = w * 2 + 1;
#pragma unroll
            for (int kb = 0; kb < 4; ++kb) {
                bf16x8 afb[4], w0[4], w1[4];
#pragma unroll
                for (int kk = 0; kk < 4; ++kk) {
                    int ks = kb * 4 + kk;
                    afb[kk] = *(const bf16x8*)(hid16 + mrow * 520 + ks * 32 + quad * 8);
                    w0[kk] = *(const bf16x8*)(Ws + (size_t)((nt0 * 16 + ks) * 64 + lane) * 8);
                    w1[kk] = *(const bf16x8*)(Ws + (size_t)((nt1 * 16 + ks) * 64 + lane) * 8);
                }
#pragma unroll
                for (int kk = 0; kk < 4; ++kk) {
                    a0 = __builtin_amdgcn_mfma_f32_16x16x32_bf16(afb[kk], w0[kk], a0, 0, 0, 0);
                    a1 = __builtin_amdgcn_mfma_f32_16x16x32_bf16(afb[kk], w1[kk], a1, 0, 0, 0);
                }
            }
            int col0 = nt0 * 16 + mrow, col1 = nt1 * 16 + mrow;
            float bb0 = bff2[l * 128 + col0], bb1 = bff2[l * 128 + col1];
#pragma unroll
            for (int r = 0; r < 4; ++r) {
                xs[(quad * 4 + r) * 128 + col0] += a0[r] + bb0;
                xs[(quad * 4 + r) * 128 + col1] += a1[r] + bb1;
            }
        }
        __syncthreads();
        ln256(xs, ln2s + l * 128, ln2b + l * 128);
    }
    for (int idx = tid; idx < 2048; idx += 256)
        out[(size_t)m * 2048 + idx] = xs[idx];
}

extern "C" void kernel_launch(void* const* d_in, const int* in_sizes, int n_in,
                              void* d_out, int out_size, void* d_ws, size_t ws_size,
                              hipStream_t stream) {
    (void)in_sizes; (void)n_in; (void)out_size; (void)ws_size;
    const int*   ego  = (const int*)d_in[0];
    const float* pos  = (const float*)d_in[1];
    const float* adj  = (const float*)d_in[2];
    const float* g1W  = (const float*)d_in[3];
    const float* g1as = (const float*)d_in[4];
    const float* g1ad = (const float*)d_in[5];
    const float* g1b  = (const float*)d_in[6];
    const float* gW   = (const float*)d_in[7];
    const float* gas  = (const float*)d_in[8];
    const float* gad  = (const float*)d_in[9];
    const float* gb   = (const float*)d_in[10];
    const float* Wqkv = (const float*)d_in[11];
    const float* bqkv = (const float*)d_in[12];
    const float* Wo   = (const float*)d_in[13];
    const float* bo   = (const float*)d_in[14];
    const float* l1s  = (const float*)d_in[15];
    const float* l1b  = (const float*)d_in[16];
    const float* l2s  = (const float*)d_in[17];
    const float* l2b  = (const float*)d_in[18];
    const float* Wff1 = (const float*)d_in[19];
    const float* bff1 = (const float*)d_in[20];
    const float* Wff2 = (const float*)d_in[21];
    const float* bff2 = (const float*)d_in[22];

    unsigned short* x0  = (unsigned short*)d_ws;       // 2,097,152 sh (4 MB)
    unsigned short* x1  = x0 + 2097152;                // 4 MB
    unsigned short* h16 = x1 + 2097152;                // 8,388,608 sh (16 MB)
    float* ssb = (float*)(h16 + 8388608);              // 65,536 f
    float* sdb = ssb + 65536;                          // 65,536 f
    float* mfl = sdb + 65536;                          // 16,384 f
    int*   cnt = (int*)(mfl + 16384);                  // 16,384 i
    int*   nbr = cnt + 16384;                          // 1,048,576 i
    unsigned short* Wb16 = (unsigned short*)(nbr + 1048576);  // 1,310,720 sh (~2.6 MB)
    unsigned short* Wg16 = Wb16 + 983040;              // GAT weight frags

    k_prep<<<640, 256, 0, stream>>>(Wqkv, Wo, Wff1, Wff2, gW, Wb16);
    k_init<<<64, 256, 0, stream>>>(ego, mfl, cnt);
    k_edges<<<1024, 256, 0, stream>>>(adj, mfl, cnt, nbr);

    // GAT layer 1 (F=2), projection + ss/sd fused
    k_gat1<<<NROWS, 128, 0, stream>>>(pos, g1W, g1as, g1ad, h16, ssb, sdb);
    k_agg<<<NROWS, 256, 0, stream>>>(h16, ssb, sdb, cnt, nbr, mfl, g1b, x0);

    unsigned short* xin = x0; unsigned short* xout = x1;
    for (int L = 0; L < 5; ++L) {
        k_gat_h<<<1024, 256, 0, stream>>>(xin, Wg16 + (size_t)L * 65536,
                                          gas + L * 512, gad + L * 512, h16, ssb, sdb);
        k_agg<<<NROWS, 256, 0, stream>>>(h16, ssb, sdb, cnt, nbr, mfl, gb + L * 128, xout);
        unsigned short* tmp = xin; xin = xout; xout = tmp;
    }

    k_tf<<<MM, 256, 0, stream>>>(xin, Wb16, bqkv, bo, l1s, l1b, l2s, l2b,
                                 bff1, bff2, (float*)d_out);
}

// Round 13
// 568.488 us; speedup vs baseline: 1.1720x; 1.1720x over previous
//
#include <hip/hip_runtime.h>
#include <hip/hip_bf16.h>

// Problem constants
#define TT 16
#define MM 1024
#define HDIM 128
#define NHEADS 4
#define NROWS (TT*MM)          // 16384
#define MAXDEG 64

typedef __bf16 bf16x8 __attribute__((ext_vector_type(8)));
typedef float f32x4 __attribute__((ext_vector_type(4)));

__device__ __forceinline__ unsigned short f2b(float x) {   // fp32 -> bf16 RNE
    unsigned u = __float_as_uint(x);
    u += 0x7fff + ((u >> 16) & 1);
    return (unsigned short)(u >> 16);
}
__device__ __forceinline__ float bu2f(unsigned short u) {
    return __uint_as_float(((unsigned)u) << 16);
}
__device__ __forceinline__ void unpk8(uint4 v, float* f) {
    f[0] = bu2f((unsigned short)(v.x & 0xffff)); f[1] = bu2f((unsigned short)(v.x >> 16));
    f[2] = bu2f((unsigned short)(v.y & 0xffff)); f[3] = bu2f((unsigned short)(v.y >> 16));
    f[4] = bu2f((unsigned short)(v.z & 0xffff)); f[5] = bu2f((unsigned short)(v.z >> 16));
    f[6] = bu2f((unsigned short)(v.w & 0xffff)); f[7] = bu2f((unsigned short)(v.w >> 16));
}

// ---------------- mask + neighbor-list build ----------------
__global__ __launch_bounds__(256) void k_init(const int* __restrict__ ego,
                                              float* __restrict__ mfl,
                                              int* __restrict__ cnt) {
    int idx = blockIdx.x * 256 + threadIdx.x;   // < 16384
    int t = idx >> 10, i = idx & 1023;
    int b = i >> 8, n = i & 255;
    mfl[idx] = ego[b * (TT * 256) + t * 256 + n] ? 1.f : 0.f;
    cnt[idx] = 0;
}

// 1024 blocks: t(16) x jc(64); thread covers 4 i via float4; 16 j-rows/block.
__global__ __launch_bounds__(256) void k_edges(const float* __restrict__ adj,
                                               const float* __restrict__ mfl,
                                               int* __restrict__ cnt,
                                               int* __restrict__ nbr) {
    int bid = blockIdx.x;
    int t = bid >> 6, jc = bid & 63;
    int tid = threadIdx.x;
    int i0 = tid * 4;
    int rowb = t * MM;
    float mi[4];
#pragma unroll
    for (int r = 0; r < 4; ++r) mi[r] = mfl[rowb + i0 + r];
    __shared__ float ms[16];
    if (tid < 16) ms[tid] = mfl[rowb + jc * 16 + tid];
    __syncthreads();
    const float* at = adj + (size_t)t * MM * MM;
#pragma unroll 4
    for (int jj = 0; jj < 16; ++jj) {
        int j = jc * 16 + jj;
        float4 a = *(const float4*)(at + (size_t)j * MM + i0);
        float mj = ms[jj];
#pragma unroll
        for (int r = 0; r < 4; ++r) {
            int i = i0 + r;
            bool e;
            if (j == i) e = (mi[r] != 0.f);                       // self-loop
            else e = ((&a.x)[r] != 0.f) && (mj != 0.f) && (mi[r] != 0.f);
            if (e) {
                int row = rowb + i;
                int pos = atomicAdd(&cnt[row], 1);
                if (pos < MAXDEG) nbr[(size_t)row * MAXDEG + pos] = j;
            }
        }
    }
}

// ---------------- weight prep: fp32 -> bf16 MFMA B-fragment order ----------------
__global__ __launch_bounds__(256) void k_prep(const float* __restrict__ Wqkv,
                                              const float* __restrict__ Wo,
                                              const float* __restrict__ Wff1,
                                              const float* __restrict__ Wff2,
                                              const float* __restrict__ gW,
                                              unsigned short* __restrict__ Wb) {
    int o = blockIdx.x * 256 + threadIdx.x;     // frag-unit (8 elems) index, < 163840
    const float* src; int cs;
    if (o < 122880) {
        int l = o / 24576, r = o % 24576;
        if (r < 6144) {                 // QKV
            int nt = r >> 8, rem = r & 255, ks = rem >> 6, lane = rem & 63;
            int mt = nt >> 3, cc = nt & 7;
            int k = ks * 32 + ((lane >> 4) << 3), c = cc * 16 + (lane & 15);
            src = Wqkv + ((size_t)(l * 3 + mt) * 128 + k) * 128 + c; cs = 128;
        } else if (r < 8192) {          // Wo
            int u = r - 6144, nt = u >> 8, rem = u & 255, ks = rem >> 6, lane = rem & 63;
            int k = ks * 32 + ((lane >> 4) << 3), c = nt * 16 + (lane & 15);
            src = Wo + (size_t)l * 16384 + (size_t)k * 128 + c; cs = 128;
        } else if (r < 16384) {         // FF1
            int u = r - 8192, nt = u >> 8, rem = u & 255, ks = rem >> 6, lane = rem & 63;
            int k = ks * 32 + ((lane >> 4) << 3), c = nt * 16 + (lane & 15);
            src = Wff1 + (size_t)l * 65536 + (size_t)k * 512 + c; cs = 512;
        } else {                        // FF2
            int u = r - 16384, nt = u >> 10, rem = u & 1023, ks = rem >> 6, lane = rem & 63;
            int k = ks * 32 + ((lane >> 4) << 3), c = nt * 16 + (lane & 15);
            src = Wff2 + (size_t)l * 65536 + (size_t)k * 128 + c; cs = 128;
        }
    } else {                            // GAT gW
        int u = o - 122880;
        int l = u >> 13, rr = u & 8191;
        int nt = rr >> 8, rem = rr & 255, ks = rem >> 6, lane = rem & 63;
        int k = ks * 32 + ((lane >> 4) << 3), c = nt * 16 + (lane & 15);
        src = gW + (size_t)l * 65536 + (size_t)k * 512 + c; cs = 512;
    }
    unsigned v[4];
#pragma unroll
    for (int j = 0; j < 4; ++j)
        v[j] = (unsigned)f2b(src[(2 * j) * (size_t)cs]) |
               ((unsigned)f2b(src[(2 * j + 1) * (size_t)cs]) << 16);
    *(uint4*)(Wb + (size_t)o * 8) = make_uint4(v[0], v[1], v[2], v[3]);
}

// ---------------- GAT layer 1: projection (F=2) + fused ss/sd; h -> bf16 ----------------
__global__ __launch_bounds__(128) void k_gat1(const float* __restrict__ x,
                                              const float* __restrict__ W,
                                              const float* __restrict__ asrc,
                                              const float* __restrict__ adst,
                                              unsigned short* __restrict__ h16,
                                              float* __restrict__ ss,
                                              float* __restrict__ sd) {
    int bid = blockIdx.x;
    int row = ((bid & 7) << 11) + (bid >> 3);   // XCD-locality swizzle
    int tid = threadIdx.x;
    float x0 = x[row * 2], x1 = x[row * 2 + 1];
    float s4[4], d4[4];
#pragma unroll
    for (int hh = 0; hh < 4; ++hh) {
        int o = hh * 128 + tid;
        float v = x0 * W[o] + x1 * W[512 + o];
        h16[(size_t)row * 512 + o] = f2b(v);
        s4[hh] = v * asrc[o];
        d4[hh] = v * adst[o];
    }
#pragma unroll
    for (int hh = 0; hh < 4; ++hh)
        for (int off = 32; off; off >>= 1) {
            s4[hh] += __shfl_down(s4[hh], off, 64);
            d4[hh] += __shfl_down(d4[hh], off, 64);
        }
    __shared__ float red[2][2][4];
    if ((tid & 63) == 0) {
        int w = tid >> 6;
#pragma unroll
        for (int hh = 0; hh < 4; ++hh) { red[w][0][hh] = s4[hh]; red[w][1][hh] = d4[hh]; }
    }
    __syncthreads();
    if (tid < 4) ss[row * 4 + tid] = red[0][0][tid] + red[1][0][tid];
    else if (tid < 8) sd[row * 4 + tid - 4] = red[0][1][tid - 4] + red[1][1][tid - 4];
}

// ---------------- GAT layers 2-6: MFMA projection + fused ss/sd ----------------
__global__ __launch_bounds__(256) void k_gat_h(const unsigned short* __restrict__ x16,
                                               const unsigned short* __restrict__ Wg,
                                               const float* __restrict__ asrc,
                                               const float* __restrict__ adst,
                                               unsigned short* __restrict__ h16,
                                               float* __restrict__ ss,
                                               float* __restrict__ sd) {
    __shared__ __align__(16) unsigned short xb[16 * 136];
    int bid = blockIdx.x;
    int row0 = (((bid & 7) << 7) + (bid >> 3)) * 16;   // band swizzle, XCD mapping
    int tid = threadIdx.x;
    {
        int rr = tid >> 4, cc = (tid & 15) * 8;
        *(uint4*)(xb + rr * 136 + cc) = *(const uint4*)(x16 + (size_t)(row0 + rr) * 128 + cc);
    }
    __syncthreads();
    const int lane = tid & 63, w = tid >> 6;
    const int mrow = lane & 15, quad = lane >> 4;
    bf16x8 af[4];
#pragma unroll
    for (int ks = 0; ks < 4; ++ks)
        af[ks] = *(const bf16x8*)(xb + mrow * 136 + ks * 32 + quad * 8);
    f32x4 acc[8];
#pragma unroll
    for (int i = 0; i < 8; ++i) acc[i] = (f32x4){0.f, 0.f, 0.f, 0.f};
#pragma unroll
    for (int ib = 0; ib < 4; ++ib) {   // batches of 2 nt x 4 ks -> 8 loads in flight
        bf16x8 wb[8];
#pragma unroll
        for (int u = 0; u < 2; ++u) {
            int nt = w * 8 + ib * 2 + u;
#pragma unroll
            for (int ks = 0; ks < 4; ++ks)
                wb[u * 4 + ks] = *(const bf16x8*)(Wg + (size_t)((nt * 4 + ks) * 64 + lane) * 8);
        }
#pragma unroll
        for (int u = 0; u < 2; ++u)
#pragma unroll
            for (int ks = 0; ks < 4; ++ks)
                acc[ib * 2 + u] = __builtin_amdgcn_mfma_f32_16x16x32_bf16(af[ks], wb[u * 4 + ks], acc[ib * 2 + u], 0, 0, 0);
    }
    float ps[4] = {0, 0, 0, 0}, pd[4] = {0, 0, 0, 0};
#pragma unroll
    for (int i = 0; i < 8; ++i) {
        int nt = w * 8 + i, col = nt * 16 + mrow;
        float as_ = asrc[col], ad_ = adst[col];
#pragma unroll
        for (int r = 0; r < 4; ++r) {
            float v = acc[i][r];
            h16[(size_t)(row0 + quad * 4 + r) * 512 + col] = f2b(v);
            ps[r] += v * as_; pd[r] += v * ad_;
        }
    }
#pragma unroll
    for (int off = 1; off < 16; off <<= 1)
#pragma unroll
        for (int r = 0; r < 4; ++r) {
            ps[r] += __shfl_xor(ps[r], off, 64);
            pd[r] += __shfl_xor(pd[r], off, 64);
        }
    if (mrow == 0) {
#pragma unroll
        for (int r = 0; r < 4; ++r) {
            int row = row0 + quad * 4 + r;
            ss[row * 4 + w] = ps[r];
            sd[row * 4 + w] = pd[r];
        }
    }
}

// -------- GAT aggregation: 256 thr, split-neighbor gather (half the serial chain) --------
__global__ __launch_bounds__(256) void k_agg(const unsigned short* __restrict__ h16,
                                             const float* __restrict__ ss,
                                             const float* __restrict__ sd,
                                             const int* __restrict__ cnt,
                                             const int* __restrict__ nbr,
                                             const float* __restrict__ mfl,
                                             const float* __restrict__ bias,
                                             unsigned short* __restrict__ xo16) {
    int bid = blockIdx.x;
    int row = ((bid & 7) << 11) + (bid >> 3);   // same-t rows colocate per XCD
    int tid = threadIdx.x;
    int t = row >> 10;
    if (mfl[row] == 0.f) { if (tid < 128) xo16[(size_t)row * 128 + tid] = 0; return; }
    int c = cnt[row]; if (c > MAXDEG) c = MAXDEG;
    __shared__ int nb[MAXDEG];
    __shared__ float al[MAXDEG][4];
    __shared__ __align__(16) float part[1024];
    if (tid < c) nb[tid] = nbr[(size_t)row * MAXDEG + tid];
    __syncthreads();
    for (int idx = tid; idx < c * 4; idx += 256) {
        int n = idx >> 2, hh = idx & 3, j = nb[n];
        float lg = sd[row * 4 + hh] + ss[(t * MM + j) * 4 + hh];
        al[n][hh] = lg > 0.f ? lg : 0.2f * lg;   // leaky_relu 0.2
    }
    __syncthreads();
    // parallel segment softmax: 32 lanes per head (threads 0-127)
    if (tid < 128) {
        int hh = tid >> 5, n0 = tid & 31;
        float v1 = (n0 < c) ? al[n0][hh] : -1e30f;
        float v2 = (n0 + 32 < c) ? al[n0 + 32][hh] : -1e30f;
        float mx = fmaxf(v1, v2);
#pragma unroll
        for (int off = 16; off; off >>= 1) mx = fmaxf(mx, __shfl_xor(mx, off, 32));
        float e1 = (n0 < c) ? __expf(v1 - mx) : 0.f;
        float e2 = (n0 + 32 < c) ? __expf(v2 - mx) : 0.f;
        float s = e1 + e2;
#pragma unroll
        for (int off = 16; off; off >>= 1) s += __shfl_xor(s, off, 32);
        float inv = 1.f / s;
        if (n0 < c) al[n0][hh] = e1 * inv;
        if (n0 + 32 < c) al[n0 + 32][hh] = e2 * inv;
    }
    __syncthreads();
    // gather: half=tid>>7 handles n = half, half+2, ...; thread owns 4 cols (uint2)
    {
        int half = tid >> 7, ct = tid & 127;
        int hh2 = ct >> 5;
        float a0 = 0.f, a1 = 0.f, a2 = 0.f, a3 = 0.f;
        const unsigned short* hbase = h16 + (size_t)t * MM * 512 + ct * 4;
#pragma unroll 2
        for (int n = half; n < c; n += 2) {
            int j = nb[n];
            uint2 v = *(const uint2*)(hbase + (size_t)j * 512);
            float w = al[n][hh2];
            a0 += w * bu2f((unsigned short)(v.x & 0xffff));
            a1 += w * bu2f((unsigned short)(v.x >> 16));
            a2 += w * bu2f((unsigned short)(v.y & 0xffff));
            a3 += w * bu2f((unsigned short)(v.y >> 16));
        }
        *(float4*)(part + tid * 4) = make_float4(a0, a1, a2, a3);
    }
    __syncthreads();
    if (tid < 128) {
        float v = 0.25f * ((part[tid] + part[512 + tid]) + (part[128 + tid] + part[640 + tid]) +
                           (part[256 + tid] + part[768 + tid]) + (part[384 + tid] + part[896 + tid]))
                + bias[tid];
        xo16[(size_t)row * 128 + tid] = f2b(fmaxf(v, 0.f));
    }
}

// ---------------- in-place LayerNorm, 16 rows x 128, 256 threads ----------------
__device__ __forceinline__ void ln256(float* xs, const float* s, const float* b) {
    int tid = threadIdx.x, row = tid >> 4, lane = tid & 15;
    float* xr = xs + row * 128;
    float sum = 0.f;
#pragma unroll
    for (int k2 = 0; k2 < 8; ++k2) sum += xr[lane + 16 * k2];
#pragma unroll
    for (int off = 8; off; off >>= 1) sum += __shfl_xor(sum, off, 16);
    float mean = sum * (1.f / 128.f);
    float vs = 0.f;
#pragma unroll
    for (int k2 = 0; k2 < 8; ++k2) { float d = xr[lane + 16 * k2] - mean; vs += d * d; }
#pragma unroll
    for (int off = 8; off; off >>= 1) vs += __shfl_xor(vs, off, 16);
    float rstd = rsqrtf(vs * (1.f / 128.f) + 1e-5f);
#pragma unroll
    for (int k2 = 0; k2 < 8; ++k2) {
        int d = lane + 16 * k2;
        float v = (xr[d] - mean) * rstd;
        xr[d] = v * s[d] + b[d];
    }
    __syncthreads();
}

// ------- 5-layer transformer: 1 seq/block, bf16 Q/K/V in LDS, batched MFMA loads --------
// LDS = 2048(xs) + 1024(sb) + 4x1088(xb16,Q,K,V) = 8320 fl = 33280 B -> 4 blocks/CU (LDS),
// grid 1024 single pass, 16 waves/CU. launch_bounds(256,2): VGPR budget 128+ (NO spills
// — (256,4) empirically clamps VGPR to 64 and spills ~300 MB to scratch; R9/R12 evidence).
__global__ __launch_bounds__(256, 2) void k_tf(const unsigned short* __restrict__ xg,
        const unsigned short* __restrict__ Wb,
        const float* __restrict__ bqkv, const float* __restrict__ bo,
        const float* __restrict__ ln1s, const float* __restrict__ ln1b,
        const float* __restrict__ ln2s, const float* __restrict__ ln2b,
        const float* __restrict__ bff1, const float* __restrict__ bff2,
        float* __restrict__ out) {
    __shared__ __align__(16) float smem[8320];
    float* xs = smem;                                       // [16][128] fp32 residual
    float* sb = smem + 2048;                                // [16tk][64] fp32 scores
    unsigned short* xb16  = (unsigned short*)(smem + 3072); // [16][136] bf16 A-operand
    unsigned short* Qb16  = (unsigned short*)(smem + 4160); // [16][136]
    unsigned short* Kb16  = (unsigned short*)(smem + 5248); // [16][136]
    unsigned short* Vb16  = (unsigned short*)(smem + 6336); // [16][136]
    unsigned short* hid16 = (unsigned short*)(smem + 4160); // [16][520], overlays Q/K/V
    const int m = blockIdx.x, tid = threadIdx.x;
    const int lane = tid & 63, w = tid >> 6;
    const int mrow = lane & 15, quad = lane >> 4;

    // load + sinusoidal PE
    for (int idx = tid; idx < 2048; idx += 256) {
        int t = idx >> 7, d = idx & 127, jj = d >> 1;
        float arg = (float)t * expf(-(float)(2 * jj) * (9.210340371976184f / 128.f));
        float pe = (d & 1) ? cosf(arg) : sinf(arg);
        xs[idx] = bu2f(xg[(size_t)t * (MM * HDIM) + (size_t)m * HDIM + d]) + pe;
    }
    __syncthreads();

    const int crow = tid >> 4, ccb = (tid & 15) * 8;   // xs->xb16 conversion slots
    for (int l = 0; l < 5; ++l) {
        const unsigned short* Wl = Wb + (size_t)l * 196608;
        // ---- xs -> xb16 ----
        {
            const float* xp = xs + crow * 128 + ccb;
            unsigned v[4];
#pragma unroll
            for (int j = 0; j < 4; ++j)
                v[j] = (unsigned)f2b(xp[2 * j]) | ((unsigned)f2b(xp[2 * j + 1]) << 16);
            *(uint4*)(xb16 + crow * 136 + ccb) = make_uint4(v[0], v[1], v[2], v[3]);
        }
        __syncthreads();
        // ---- QKV via MFMA: wave w does nt = 6w..6w+5, batched loads; Q/K/V -> bf16 ----
        {
            bf16x8 af[4];
#pragma unroll
            for (int ks = 0; ks < 4; ++ks)
                af[ks] = *(const bf16x8*)(xb16 + mrow * 136 + ks * 32 + quad * 8);
            f32x4 acc[6];
#pragma unroll
            for (int i = 0; i < 6; ++i) acc[i] = (f32x4){0.f, 0.f, 0.f, 0.f};
#pragma unroll
            for (int ib = 0; ib < 3; ++ib) {
                bf16x8 wb[8];
#pragma unroll
                for (int u = 0; u < 2; ++u) {
                    int nt = w * 6 + ib * 2 + u;
                    const unsigned short* bp = Wl + (size_t)(nt * 4) * 512 + lane * 8;
#pragma unroll
                    for (int ks = 0; ks < 4; ++ks)
                        wb[u * 4 + ks] = *(const bf16x8*)(bp + ks * 512);
                }
#pragma unroll
                for (int u = 0; u < 2; ++u)
#pragma unroll
                    for (int ks = 0; ks < 4; ++ks)
                        acc[ib * 2 + u] = __builtin_amdgcn_mfma_f32_16x16x32_bf16(af[ks], wb[u * 4 + ks], acc[ib * 2 + u], 0, 0, 0);
            }
#pragma unroll
            for (int i = 0; i < 6; ++i) {
                int nt = w * 6 + i, mt = nt >> 3, cc = nt & 7;
                int col = cc * 16 + mrow;
                float bb = bqkv[l * 384 + mt * 128 + col];
                unsigned short* dst = (mt == 0) ? Qb16 : (mt == 1) ? Kb16 : Vb16;
#pragma unroll
                for (int r = 0; r < 4; ++r)
                    dst[(quad * 4 + r) * 136 + col] = f2b(acc[i][r] + bb);
            }
        }
        __syncthreads();
        // ---- scores (fp32 VALU, bf16 Q/K): thread = (hh, tq, tk0..tk0+3) ----
        {
            int hh = tid >> 6, tq = (tid >> 2) & 15, tk0 = (tid & 3) * 4;
            const unsigned short* qp = Qb16 + tq * 136 + hh * 32;
            float a[4] = {0.f, 0.f, 0.f, 0.f};
#pragma unroll
            for (int d4 = 0; d4 < 4; ++d4) {
                uint4 qv = *(const uint4*)(qp + d4 * 8);
                float qf[8]; unpk8(qv, qf);
#pragma unroll
                for (int j = 0; j < 4; ++j) {
                    uint4 kv = *(const uint4*)(Kb16 + (tk0 + j) * 136 + hh * 32 + d4 * 8);
                    float kf[8]; unpk8(kv, kf);
#pragma unroll
                    for (int e = 0; e < 8; ++e) a[j] += qf[e] * kf[e];
                }
            }
#pragma unroll
            for (int j = 0; j < 4; ++j)
                sb[(tk0 + j) * 64 + hh * 16 + tq] = a[j] * 0.17677669529663687f;
        }
        __syncthreads();
        if (tid < 64) {   // softmax per (hh,tq) column
            float mx = -1e30f;
#pragma unroll
            for (int u = 0; u < 16; ++u) mx = fmaxf(mx, sb[u * 64 + tid]);
            float s = 0.f;
#pragma unroll
            for (int u = 0; u < 16; ++u) { float e = __expf(sb[u * 64 + tid] - mx); sb[u * 64 + tid] = e; s += e; }
            float inv = 1.f / s;
#pragma unroll
            for (int u = 0; u < 16; ++u) sb[u * 64 + tid] *= inv;
        }
        __syncthreads();
        // ---- O = P @ V (fp32, bf16 V) -> xb16 ----
        {
            int o = tid & 127, r0p = (tid >> 7) * 8, hh = o >> 5;
            float accp[8] = {0, 0, 0, 0, 0, 0, 0, 0};
            for (int u = 0; u < 16; ++u) {
                float vv = bu2f(Vb16[u * 136 + o]);
                const float* pp = sb + u * 64 + hh * 16 + r0p;
#pragma unroll
                for (int r = 0; r < 8; ++r) accp[r] += pp[r] * vv;
            }
#pragma unroll
            for (int r = 0; r < 8; ++r)
                xb16[(r0p + r) * 136 + o] = f2b(accp[r]);
        }
        __syncthreads();
        // ---- Wo via MFMA: wave w does nt = 2w, 2w+1; one batch of 8 loads ----
        {
            bf16x8 af[4];
#pragma unroll
            for (int ks = 0; ks < 4; ++ks)
                af[ks] = *(const bf16x8*)(xb16 + mrow * 136 + ks * 32 + quad * 8);
            const unsigned short* Ws = Wl + 49152;
            bf16x8 wb[8];
#pragma unroll
            for (int u = 0; u < 2; ++u) {
                int nt = w * 2 + u;
#pragma unroll
                for (int ks = 0; ks < 4; ++ks)
                    wb[u * 4 + ks] = *(const bf16x8*)(Ws + (size_t)((nt * 4 + ks) * 64 + lane) * 8);
            }
            f32x4 acc[2];
            acc[0] = (f32x4){0.f, 0.f, 0.f, 0.f};
            acc[1] = (f32x4){0.f, 0.f, 0.f, 0.f};
#pragma unroll
            for (int u = 0; u < 2; ++u)
#pragma unroll
                for (int ks = 0; ks < 4; ++ks)
                    acc[u] = __builtin_amdgcn_mfma_f32_16x16x32_bf16(af[ks], wb[u * 4 + ks], acc[u], 0, 0, 0);
#pragma unroll
            for (int u = 0; u < 2; ++u) {
                int col = (w * 2 + u) * 16 + mrow;
                float bb = bo[l * 128 + col];
#pragma unroll
                for (int r = 0; r < 4; ++r)
                    xs[(quad * 4 + r) * 128 + col] += acc[u][r] + bb;
            }
        }
        __syncthreads();
        ln256(xs, ln1s + l * 128, ln1b + l * 128);
        // ---- xs -> xb16 (post-LN1) ----
        {
            const float* xp = xs + crow * 128 + ccb;
            unsigned v[4];
#pragma unroll
            for (int j = 0; j < 4; ++j)
                v[j] = (unsigned)f2b(xp[2 * j]) | ((unsigned)f2b(xp[2 * j + 1]) << 16);
            *(uint4*)(xb16 + crow * 136 + ccb) = make_uint4(v[0], v[1], v[2], v[3]);
        }
        __syncthreads();
        // ---- FF1 via MFMA: wave w does nt = 8w..8w+7, batched; relu -> hid16 ----
        {
            bf16x8 af[4];
#pragma unroll
            for (int ks = 0; ks < 4; ++ks)
                af[ks] = *(const bf16x8*)(xb16 + mrow * 136 + ks * 32 + quad * 8);
            f32x4 acc[8];
#pragma unroll
            for (int i = 0; i < 8; ++i) acc[i] = (f32x4){0.f, 0.f, 0.f, 0.f};
            const unsigned short* Ws = Wl + 65536;
#pragma unroll
            for (int ib = 0; ib < 4; ++ib) {
                bf16x8 wb[8];
#pragma unroll
                for (int u = 0; u < 2; ++u) {
                    int nt = w * 8 + ib * 2 + u;
#pragma unroll
                    for (int ks = 0; ks < 4; ++ks)
                        wb[u * 4 + ks] = *(const bf16x8*)(Ws + (size_t)((nt * 4 + ks) * 64 + lane) * 8);
                }
#pragma unroll
                for (int u = 0; u < 2; ++u)
#pragma unroll
                    for (int ks = 0; ks < 4; ++ks)
                        acc[ib * 2 + u] = __builtin_amdgcn_mfma_f32_16x16x32_bf16(af[ks], wb[u * 4 + ks], acc[ib * 2 + u], 0, 0, 0);
            }
#pragma unroll
            for (int i = 0; i < 8; ++i) {
                int col = (w * 8 + i) * 16 + mrow;
                float bb = bff1[l * 512 + col];
#pragma unroll
                for (int r = 0; r < 4; ++r) {
                    float v = fmaxf(acc[i][r] + bb, 0.f);
                    hid16[(quad * 4 + r) * 520 + col] = f2b(v);
                }
            }
        }
        __syncthreads();
        // ---- FF2 via MFMA: 2 nt x 16 ks per wave, batched 4 ks at a time ----
        {
            f32x4 a0 = (f32x4){0.f, 0.f, 0.f, 0.f};
            f32x4 a1 = (f32x4){0.f, 0.f, 0.f, 0.f};
            const unsigned short* Ws = Wl + 131072;
            int nt0 = w * 2, nt1 = w * 2 + 1;
#pragma unroll
            for (int kb = 0; kb < 4; ++kb) {
                bf16x8 afb[4], w0[4], w1[4];
#pragma unroll
                for (int kk = 0; kk < 4; ++kk) {
                    int ks = kb * 4 + kk;
                    afb[kk] = *(const bf16x8*)(hid16 + mrow * 520 + ks * 32 + quad * 8);
                    w0[kk] = *(const bf16x8*)(Ws + (size_t)((nt0 * 16 + ks) * 64 + lane) * 8);
                    w1[kk] = *(const bf16x8*)(Ws + (size_t)((nt1 * 16 + ks) * 64 + lane) * 8);
                }
#pragma unroll
                for (int kk = 0; kk < 4; ++kk) {
                    a0 = __builtin_amdgcn_mfma_f32_16x16x32_bf16(afb[kk], w0[kk], a0, 0, 0, 0);
                    a1 = __builtin_amdgcn_mfma_f32_16x16x32_bf16(afb[kk], w1[kk], a1, 0, 0, 0);
                }
            }
            int col0 = nt0 * 16 + mrow, col1 = nt1 * 16 + mrow;
            float bb0 = bff2[l * 128 + col0], bb1 = bff2[l * 128 + col1];
#pragma unroll
            for (int r = 0; r < 4; ++r) {
                xs[(quad * 4 + r) * 128 + col0] += a0[r] + bb0;
                xs[(quad * 4 + r) * 128 + col1] += a1[r] + bb1;
            }
        }
        __syncthreads();
        ln256(xs, ln2s + l * 128, ln2b + l * 128);
    }
    for (int idx = tid; idx < 2048; idx += 256)
        out[(size_t)m * 2048 + idx] = xs[idx];
}

extern "C" void kernel_launch(void* const* d_in, const int* in_sizes, int n_in,
                              void* d_out, int out_size, void* d_ws, size_t ws_size,
                              hipStream_t stream) {
    (void)in_sizes; (void)n_in; (void)out_size; (void)ws_size;
    const int*   ego  = (const int*)d_in[0];
    const float* pos  = (const float*)d_in[1];
    const float* adj  = (const float*)d_in[2];
    const float* g1W  = (const float*)d_in[3];
    const float* g1as = (const float*)d_in[4];
    const float* g1ad = (const float*)d_in[5];
    const float* g1b  = (const float*)d_in[6];
    const float* gW   = (const float*)d_in[7];
    const float* gas  = (const float*)d_in[8];
    const float* gad  = (const float*)d_in[9];
    const float* gb   = (const float*)d_in[10];
    const float* Wqkv = (const float*)d_in[11];
    const float* bqkv = (const float*)d_in[12];
    const float* Wo   = (const float*)d_in[13];
    const float* bo   = (const float*)d_in[14];
    const float* l1s  = (const float*)d_in[15];
    const float* l1b  = (const float*)d_in[16];
    const float* l2s  = (const float*)d_in[17];
    const float* l2b  = (const float*)d_in[18];
    const float* Wff1 = (const float*)d_in[19];
    const float* bff1 = (const float*)d_in[20];
    const float* Wff2 = (const float*)d_in[21];
    const float* bff2 = (const float*)d_in[22];

    unsigned short* x0  = (unsigned short*)d_ws;       // 2,097,152 sh (4 MB)
    unsigned short* x1  = x0 + 2097152;                // 4 MB
    unsigned short* h16 = x1 + 2097152;                // 8,388,608 sh (16 MB)
    float* ssb = (float*)(h16 + 8388608);              // 65,536 f
    float* sdb = ssb + 65536;                          // 65,536 f
    float* mfl = sdb + 65536;                          // 16,384 f
    int*   cnt = (int*)(mfl + 16384);                  // 16,384 i
    int*   nbr = cnt + 16384;                          // 1,048,576 i
    unsigned short* Wb16 = (unsigned short*)(nbr + 1048576);  // 1,310,720 sh (~2.6 MB)
    unsigned short* Wg16 = Wb16 + 983040;              // GAT weight frags

    k_prep<<<640, 256, 0, stream>>>(Wqkv, Wo, Wff1, Wff2, gW, Wb16);
    k_init<<<64, 256, 0, stream>>>(ego, mfl, cnt);
    k_edges<<<1024, 256, 0, stream>>>(adj, mfl, cnt, nbr);

    // GAT layer 1 (F=2), projection + ss/sd fused
    k_gat1<<<NROWS, 128, 0, stream>>>(pos, g1W, g1as, g1ad, h16, ssb, sdb);
    k_agg<<<NROWS, 256, 0, stream>>>(h16, ssb, sdb, cnt, nbr, mfl, g1b, x0);

    unsigned short* xin = x0; unsigned short* xout = x1;
    for (int L = 0; L < 5; ++L) {
        k_gat_h<<<1024, 256, 0, stream>>>(xin, Wg16 + (size_t)L * 65536,
                                          gas + L * 512, gad + L * 512, h16, ssb, sdb);
        k_agg<<<NROWS, 256, 0, stream>>>(h16, ssb, sdb, cnt, nbr, mfl, gb + L * 128, xout);
        unsigned short* tmp = xin; xin = xout; xout = tmp;
    }

    k_tf<<<MM, 256, 0, stream>>>(xin, Wb16, bqkv, bo, l1s, l1b, l2s, l2b,
                                 bff1, bff2, (float*)d_out);
}

// Round 14
// 508.002 us; speedup vs baseline: 1.3116x; 1.1191x over previous
//
#include <hip/hip_runtime.h>
#include <hip/hip_bf16.h>

// Problem constants
#define TT 16
#define MM 1024
#define HDIM 128
#define NHEADS 4
#define NROWS (TT*MM)          // 16384
#define MAXDEG 64

typedef __bf16 bf16x8 __attribute__((ext_vector_type(8)));
typedef float f32x4 __attribute__((ext_vector_type(4)));

__device__ __forceinline__ unsigned short f2b(float x) {   // fp32 -> bf16 RNE
    unsigned u = __float_as_uint(x);
    u += 0x7fff + ((u >> 16) & 1);
    return (unsigned short)(u >> 16);
}
__device__ __forceinline__ float bu2f(unsigned short u) {
    return __uint_as_float(((unsigned)u) << 16);
}

// ---------------- mask + neighbor-list build ----------------
__global__ __launch_bounds__(256) void k_init(const int* __restrict__ ego,
                                              float* __restrict__ mfl,
                                              int* __restrict__ cnt) {
    int idx = blockIdx.x * 256 + threadIdx.x;   // < 16384
    int t = idx >> 10, i = idx & 1023;
    int b = i >> 8, n = i & 255;
    mfl[idx] = ego[b * (TT * 256) + t * 256 + n] ? 1.f : 0.f;
    cnt[idx] = 0;
}

// 1024 blocks: t(16) x jc(64); thread covers 4 i via float4; 16 j-rows/block.
__global__ __launch_bounds__(256) void k_edges(const float* __restrict__ adj,
                                               const float* __restrict__ mfl,
                                               int* __restrict__ cnt,
                                               int* __restrict__ nbr) {
    int bid = blockIdx.x;
    int t = bid >> 6, jc = bid & 63;
    int tid = threadIdx.x;
    int i0 = tid * 4;
    int rowb = t * MM;
    float mi[4];
#pragma unroll
    for (int r = 0; r < 4; ++r) mi[r] = mfl[rowb + i0 + r];
    __shared__ float ms[16];
    if (tid < 16) ms[tid] = mfl[rowb + jc * 16 + tid];
    __syncthreads();
    const float* at = adj + (size_t)t * MM * MM;
#pragma unroll 4
    for (int jj = 0; jj < 16; ++jj) {
        int j = jc * 16 + jj;
        float4 a = *(const float4*)(at + (size_t)j * MM + i0);
        float mj = ms[jj];
#pragma unroll
        for (int r = 0; r < 4; ++r) {
            int i = i0 + r;
            bool e;
            if (j == i) e = (mi[r] != 0.f);                       // self-loop
            else e = ((&a.x)[r] != 0.f) && (mj != 0.f) && (mi[r] != 0.f);
            if (e) {
                int row = rowb + i;
                int pos = atomicAdd(&cnt[row], 1);
                if (pos < MAXDEG) nbr[(size_t)row * MAXDEG + pos] = j;
            }
        }
    }
}

// ---------------- weight prep: fp32 -> bf16 MFMA B-fragment order ----------------
__global__ __launch_bounds__(256) void k_prep(const float* __restrict__ Wqkv,
                                              const float* __restrict__ Wo,
                                              const float* __restrict__ Wff1,
                                              const float* __restrict__ Wff2,
                                              const float* __restrict__ gW,
                                              unsigned short* __restrict__ Wb) {
    int o = blockIdx.x * 256 + threadIdx.x;     // frag-unit (8 elems) index, < 163840
    const float* src; int cs;
    if (o < 122880) {
        int l = o / 24576, r = o % 24576;
        if (r < 6144) {                 // QKV
            int nt = r >> 8, rem = r & 255, ks = rem >> 6, lane = rem & 63;
            int mt = nt >> 3, cc = nt & 7;
            int k = ks * 32 + ((lane >> 4) << 3), c = cc * 16 + (lane & 15);
            src = Wqkv + ((size_t)(l * 3 + mt) * 128 + k) * 128 + c; cs = 128;
        } else if (r < 8192) {          // Wo
            int u = r - 6144, nt = u >> 8, rem = u & 255, ks = rem >> 6, lane = rem & 63;
            int k = ks * 32 + ((lane >> 4) << 3), c = nt * 16 + (lane & 15);
            src = Wo + (size_t)l * 16384 + (size_t)k * 128 + c; cs = 128;
        } else if (r < 16384) {         // FF1
            int u = r - 8192, nt = u >> 8, rem = u & 255, ks = rem >> 6, lane = rem & 63;
            int k = ks * 32 + ((lane >> 4) << 3), c = nt * 16 + (lane & 15);
            src = Wff1 + (size_t)l * 65536 + (size_t)k * 512 + c; cs = 512;
        } else {                        // FF2
            int u = r - 16384, nt = u >> 10, rem = u & 1023, ks = rem >> 6, lane = rem & 63;
            int k = ks * 32 + ((lane >> 4) << 3), c = nt * 16 + (lane & 15);
            src = Wff2 + (size_t)l * 65536 + (size_t)k * 128 + c; cs = 128;
        }
    } else {                            // GAT gW
        int u = o - 122880;
        int l = u >> 13, rr = u & 8191;
        int nt = rr >> 8, rem = rr & 255, ks = rem >> 6, lane = rem & 63;
        int k = ks * 32 + ((lane >> 4) << 3), c = nt * 16 + (lane & 15);
        src = gW + (size_t)l * 65536 + (size_t)k * 512 + c; cs = 512;
    }
    unsigned v[4];
#pragma unroll
    for (int j = 0; j < 4; ++j)
        v[j] = (unsigned)f2b(src[(2 * j) * (size_t)cs]) |
               ((unsigned)f2b(src[(2 * j + 1) * (size_t)cs]) << 16);
    *(uint4*)(Wb + (size_t)o * 8) = make_uint4(v[0], v[1], v[2], v[3]);
}

// ---------------- GAT layer 1: projection (F=2) + fused ss/sd; h -> bf16 ----------------
__global__ __launch_bounds__(128) void k_gat1(const float* __restrict__ x,
                                              const float* __restrict__ W,
                                              const float* __restrict__ asrc,
                                              const float* __restrict__ adst,
                                              unsigned short* __restrict__ h16,
                                              float* __restrict__ ss,
                                              float* __restrict__ sd) {
    int bid = blockIdx.x;
    int row = ((bid & 7) << 11) + (bid >> 3);   // XCD-locality swizzle
    int tid = threadIdx.x;
    float x0 = x[row * 2], x1 = x[row * 2 + 1];
    float s4[4], d4[4];
#pragma unroll
    for (int hh = 0; hh < 4; ++hh) {
        int o = hh * 128 + tid;
        float v = x0 * W[o] + x1 * W[512 + o];
        h16[(size_t)row * 512 + o] = f2b(v);
        s4[hh] = v * asrc[o];
        d4[hh] = v * adst[o];
    }
#pragma unroll
    for (int hh = 0; hh < 4; ++hh)
        for (int off = 32; off; off >>= 1) {
            s4[hh] += __shfl_down(s4[hh], off, 64);
            d4[hh] += __shfl_down(d4[hh], off, 64);
        }
    __shared__ float red[2][2][4];
    if ((tid & 63) == 0) {
        int w = tid >> 6;
#pragma unroll
        for (int hh = 0; hh < 4; ++hh) { red[w][0][hh] = s4[hh]; red[w][1][hh] = d4[hh]; }
    }
    __syncthreads();
    if (tid < 4) ss[row * 4 + tid] = red[0][0][tid] + red[1][0][tid];
    else if (tid < 8) sd[row * 4 + tid - 4] = red[0][1][tid - 4] + red[1][1][tid - 4];
}

// ------- GAT layers 2-6: MFMA projection, 32 rows/block, weight-amortized ----------
// grid 512; wave w owns head w; ib-outer loop: each 8-frag weight batch feeds 2 row-groups.
__global__ __launch_bounds__(256, 2) void k_gat_h(const unsigned short* __restrict__ x16,
                                                  const unsigned short* __restrict__ Wg,
                                                  const float* __restrict__ asrc,
                                                  const float* __restrict__ adst,
                                                  unsigned short* __restrict__ h16,
                                                  float* __restrict__ ss,
                                                  float* __restrict__ sd) {
    __shared__ __align__(16) unsigned short xb[32 * 136];
    int bid = blockIdx.x;
    int row0 = (((bid & 7) << 6) + (bid >> 3)) * 32;   // XCD swizzle (2 t-slices per XCD)
    int tid = threadIdx.x;
#pragma unroll
    for (int q = 0; q < 2; ++q) {
        int u = tid + q * 256;          // 0..511 frag units of 8 shorts
        int rr = u >> 4, cc = (u & 15) * 8;
        *(uint4*)(xb + rr * 136 + cc) = *(const uint4*)(x16 + (size_t)(row0 + rr) * 128 + cc);
    }
    __syncthreads();
    const int lane = tid & 63, w = tid >> 6;
    const int mrow = lane & 15, quad = lane >> 4;
    float ps[2][4] = {{0,0,0,0},{0,0,0,0}}, pd[2][4] = {{0,0,0,0},{0,0,0,0}};
#pragma unroll
    for (int ib = 0; ib < 4; ++ib) {
        bf16x8 wb[8];
#pragma unroll
        for (int u = 0; u < 2; ++u) {
            int nt = w * 8 + ib * 2 + u;
#pragma unroll
            for (int ks = 0; ks < 4; ++ks)
                wb[u * 4 + ks] = *(const bf16x8*)(Wg + (size_t)((nt * 4 + ks) * 64 + lane) * 8);
        }
#pragma unroll
        for (int rg = 0; rg < 2; ++rg) {
            bf16x8 af[4];
#pragma unroll
            for (int ks = 0; ks < 4; ++ks)
                af[ks] = *(const bf16x8*)(xb + (rg * 16 + mrow) * 136 + ks * 32 + quad * 8);
            f32x4 acc[2];
            acc[0] = (f32x4){0.f, 0.f, 0.f, 0.f};
            acc[1] = (f32x4){0.f, 0.f, 0.f, 0.f};
#pragma unroll
            for (int u = 0; u < 2; ++u)
#pragma unroll
                for (int ks = 0; ks < 4; ++ks)
                    acc[u] = __builtin_amdgcn_mfma_f32_16x16x32_bf16(af[ks], wb[u * 4 + ks], acc[u], 0, 0, 0);
#pragma unroll
            for (int u = 0; u < 2; ++u) {
                int nt = w * 8 + ib * 2 + u, col = nt * 16 + mrow;
                float as_ = asrc[col], ad_ = adst[col];
#pragma unroll
                for (int r = 0; r < 4; ++r) {
                    float v = acc[u][r];
                    h16[(size_t)(row0 + rg * 16 + quad * 4 + r) * 512 + col] = f2b(v);
                    ps[rg][r] += v * as_; pd[rg][r] += v * ad_;
                }
            }
        }
    }
#pragma unroll
    for (int off = 1; off < 16; off <<= 1)
#pragma unroll
        for (int rg = 0; rg < 2; ++rg)
#pragma unroll
            for (int r = 0; r < 4; ++r) {
                ps[rg][r] += __shfl_xor(ps[rg][r], off, 64);
                pd[rg][r] += __shfl_xor(pd[rg][r], off, 64);
            }
    if (mrow == 0) {
#pragma unroll
        for (int rg = 0; rg < 2; ++rg)
#pragma unroll
            for (int r = 0; r < 4; ++r) {
                int row = row0 + rg * 16 + quad * 4 + r;
                ss[row * 4 + w] = ps[rg][r];
                sd[row * 4 + w] = pd[rg][r];
            }
    }
}

// -------- GAT aggregation: wave-per-row, 4 rows per 256-thr block, grid 4096 --------
// Softmax fully in-register (64-lane shfl); one LDS handoff alpha/nb -> gather layout;
// gather = one uint4 (8 bf16) per lane per neighbor.
__global__ __launch_bounds__(256, 2) void k_agg(const unsigned short* __restrict__ h16,
                                                const float* __restrict__ ss,
                                                const float* __restrict__ sd,
                                                const int* __restrict__ cnt,
                                                const int* __restrict__ nbr,
                                                const float* __restrict__ mfl,
                                                const float* __restrict__ bias,
                                                unsigned short* __restrict__ xo16) {
    __shared__ float alB[4][MAXDEG][4];
    __shared__ int   nbB[4][MAXDEG];
    __shared__ __align__(16) float partB[4][512];
    int bid = blockIdx.x;
    int row0 = (((bid & 7) << 9) + (bid >> 3)) * 4;   // XCD swizzle
    int tid = threadIdx.x;
    const int w = tid >> 6, lane = tid & 63;
    int row = row0 + w, t = row >> 10;
    bool valid = mfl[row] != 0.f;
    int c = 0;
    if (valid) { c = cnt[row]; if (c > MAXDEG) c = MAXDEG; }
    // ---- per-lane logits + in-register softmax ----
    bool act = lane < c;
    int jreg = 0;
    float lg[4];
    if (act) {
        jreg = nbr[(size_t)row * MAXDEG + lane];
        int jr = t * MM + jreg;
#pragma unroll
        for (int hh = 0; hh < 4; ++hh) {
            float v = sd[row * 4 + hh] + ss[jr * 4 + hh];
            lg[hh] = v > 0.f ? v : 0.2f * v;      // leaky_relu 0.2
        }
    } else {
#pragma unroll
        for (int hh = 0; hh < 4; ++hh) lg[hh] = -1e30f;
    }
    float mx[4];
#pragma unroll
    for (int hh = 0; hh < 4; ++hh) mx[hh] = lg[hh];
#pragma unroll
    for (int off = 32; off; off >>= 1)
#pragma unroll
        for (int hh = 0; hh < 4; ++hh) mx[hh] = fmaxf(mx[hh], __shfl_xor(mx[hh], off, 64));
    float ev[4];
#pragma unroll
    for (int hh = 0; hh < 4; ++hh) ev[hh] = act ? __expf(lg[hh] - mx[hh]) : 0.f;
    float sm[4];
#pragma unroll
    for (int hh = 0; hh < 4; ++hh) sm[hh] = ev[hh];
#pragma unroll
    for (int off = 32; off; off >>= 1)
#pragma unroll
        for (int hh = 0; hh < 4; ++hh) sm[hh] += __shfl_xor(sm[hh], off, 64);
    if (act) {
        float4 a4 = make_float4(ev[0] / sm[0], ev[1] / sm[1], ev[2] / sm[2], ev[3] / sm[3]);
        *(float4*)&alB[w][lane][0] = a4;
        nbB[w][lane] = jreg;
    }
    __syncthreads();
    // ---- gather: lane owns 8 cols (uint4 per neighbor) ----
    const int head = lane >> 4;
    float acc[8] = {0, 0, 0, 0, 0, 0, 0, 0};
    const unsigned short* hb = h16 + (size_t)t * MM * 512 + lane * 8;
    for (int n = 0; n < c; ++n) {
        int j = nbB[w][n];                 // broadcast LDS read
        float a = alB[w][n][head];
        uint4 v = *(const uint4*)(hb + (size_t)j * 512);
        acc[0] += a * bu2f((unsigned short)(v.x & 0xffff));
        acc[1] += a * bu2f((unsigned short)(v.x >> 16));
        acc[2] += a * bu2f((unsigned short)(v.y & 0xffff));
        acc[3] += a * bu2f((unsigned short)(v.y >> 16));
        acc[4] += a * bu2f((unsigned short)(v.z & 0xffff));
        acc[5] += a * bu2f((unsigned short)(v.z >> 16));
        acc[6] += a * bu2f((unsigned short)(v.w & 0xffff));
        acc[7] += a * bu2f((unsigned short)(v.w >> 16));
    }
    *(float4*)&partB[w][lane * 8]     = make_float4(acc[0], acc[1], acc[2], acc[3]);
    *(float4*)&partB[w][lane * 8 + 4] = make_float4(acc[4], acc[5], acc[6], acc[7]);
    __syncthreads();
    // ---- head-mean + bias + relu; lane handles 2 cols ----
    {
        int d0 = lane * 2;
        unsigned outp = 0;
#pragma unroll
        for (int q = 0; q < 2; ++q) {
            int d = d0 + q;
            float v = 0.f;
            if (valid) {
                v = 0.25f * (partB[w][d] + partB[w][128 + d] + partB[w][256 + d] + partB[w][384 + d])
                    + bias[d];
                v = fmaxf(v, 0.f);
            }
            outp |= ((unsigned)f2b(v)) << (16 * q);
        }
        *(unsigned*)(xo16 + (size_t)row * 128 + d0) = outp;
    }
}

// ---------------- in-place LayerNorm, 16 rows x 128, 256 threads ----------------
__device__ __forceinline__ void ln256(float* xs, const float* s, const float* b) {
    int tid = threadIdx.x, row = tid >> 4, lane = tid & 15;
    float* xr = xs + row * 128;
    float sum = 0.f;
#pragma unroll
    for (int k2 = 0; k2 < 8; ++k2) sum += xr[lane + 16 * k2];
#pragma unroll
    for (int off = 8; off; off >>= 1) sum += __shfl_xor(sum, off, 16);
    float mean = sum * (1.f / 128.f);
    float vs = 0.f;
#pragma unroll
    for (int k2 = 0; k2 < 8; ++k2) { float d = xr[lane + 16 * k2] - mean; vs += d * d; }
#pragma unroll
    for (int off = 8; off; off >>= 1) vs += __shfl_xor(vs, off, 16);
    float rstd = rsqrtf(vs * (1.f / 128.f) + 1e-5f);
#pragma unroll
    for (int k2 = 0; k2 < 8; ++k2) {
        int d = lane + 16 * k2;
        float v = (xr[d] - mean) * rstd;
        xr[d] = v * s[d] + b[d];
    }
    __syncthreads();
}

// ------- 5-layer transformer: 1 seq/block, bf16 Q/K/V in LDS, batched MFMA loads --------
// LDS 33280 B; launch_bounds(256,2): VGPR 112, no spills (R13 verified).
__global__ __launch_bounds__(256, 2) void k_tf(const unsigned short* __restrict__ xg,
        const unsigned short* __restrict__ Wb,
        const float* __restrict__ bqkv, const float* __restrict__ bo,
        const float* __restrict__ ln1s, const float* __restrict__ ln1b,
        const float* __restrict__ ln2s, const float* __restrict__ ln2b,
        const float* __restrict__ bff1, const float* __restrict__ bff2,
        float* __restrict__ out) {
    __shared__ __align__(16) float smem[8320];
    float* xs = smem;                                       // [16][128] fp32 residual
    float* sb = smem + 2048;                                // [16tk][64] fp32 scores
    unsigned short* xb16  = (unsigned short*)(smem + 3072); // [16][136] bf16 A-operand
    unsigned short* Qb16  = (unsigned short*)(smem + 4160); // [16][136]
    unsigned short* Kb16  = (unsigned short*)(smem + 5248); // [16][136]
    unsigned short* Vb16  = (unsigned short*)(smem + 6336); // [16][136]
    unsigned short* hid16 = (unsigned short*)(smem + 4160); // [16][520], overlays Q/K/V
    const int m = blockIdx.x, tid = threadIdx.x;
    const int lane = tid & 63, w = tid >> 6;
    const int mrow = lane & 15, quad = lane >> 4;

    // load + sinusoidal PE
    for (int idx = tid; idx < 2048; idx += 256) {
        int t = idx >> 7, d = idx & 127, jj = d >> 1;
        float arg = (float)t * expf(-(float)(2 * jj) * (9.210340371976184f / 128.f));
        float pe = (d & 1) ? cosf(arg) : sinf(arg);
        xs[idx] = bu2f(xg[(size_t)t * (MM * HDIM) + (size_t)m * HDIM + d]) + pe;
    }
    __syncthreads();

    const int crow = tid >> 4, ccb = (tid & 15) * 8;   // xs->xb16 conversion slots
    for (int l = 0; l < 5; ++l) {
        const unsigned short* Wl = Wb + (size_t)l * 196608;
        // ---- xs -> xb16 ----
        {
            const float* xp = xs + crow * 128 + ccb;
            unsigned v[4];
#pragma unroll
            for (int j = 0; j < 4; ++j)
                v[j] = (unsigned)f2b(xp[2 * j]) | ((unsigned)f2b(xp[2 * j + 1]) << 16);
            *(uint4*)(xb16 + crow * 136 + ccb) = make_uint4(v[0], v[1], v[2], v[3]);
        }
        __syncthreads();
        // ---- QKV via MFMA: wave w does nt = 6w..6w+5, batched loads; Q/K/V -> bf16 ----
        {
            bf16x8 af[4];
#pragma unroll
            for (int ks = 0; ks < 4; ++ks)
                af[ks] = *(const bf16x8*)(xb16 + mrow * 136 + ks * 32 + quad * 8);
            f32x4 acc[6];
#pragma unroll
            for (int i = 0; i < 6; ++i) acc[i] = (f32x4){0.f, 0.f, 0.f, 0.f};
#pragma unroll
            for (int ib = 0; ib < 3; ++ib) {
                bf16x8 wb[8];
#pragma unroll
                for (int u = 0; u < 2; ++u) {
                    int nt = w * 6 + ib * 2 + u;
                    const unsigned short* bp = Wl + (size_t)(nt * 4) * 512 + lane * 8;
#pragma unroll
                    for (int ks = 0; ks < 4; ++ks)
                        wb[u * 4 + ks] = *(const bf16x8*)(bp + ks * 512);
                }
#pragma unroll
                for (int u = 0; u < 2; ++u)
#pragma unroll
                    for (int ks = 0; ks < 4; ++ks)
                        acc[ib * 2 + u] = __builtin_amdgcn_mfma_f32_16x16x32_bf16(af[ks], wb[u * 4 + ks], acc[ib * 2 + u], 0, 0, 0);
            }
#pragma unroll
            for (int i = 0; i < 6; ++i) {
                int nt = w * 6 + i, mt = nt >> 3, cc = nt & 7;
                int col = cc * 16 + mrow;
                float bb = bqkv[l * 384 + mt * 128 + col];
                unsigned short* dst = (mt == 0) ? Qb16 : (mt == 1) ? Kb16 : Vb16;
#pragma unroll
                for (int r = 0; r < 4; ++r)
                    dst[(quad * 4 + r) * 136 + col] = f2b(acc[i][r] + bb);
            }
        }
        __syncthreads();
        // ---- scores (fp32 VALU, bf16 Q/K): thread = (hh, tq, tk0..tk0+3) ----
        {
            int hh = tid >> 6, tq = (tid >> 2) & 15, tk0 = (tid & 3) * 4;
            const unsigned short* qp = Qb16 + tq * 136 + hh * 32;
            float a[4] = {0.f, 0.f, 0.f, 0.f};
#pragma unroll
            for (int d4 = 0; d4 < 4; ++d4) {
                uint4 qv = *(const uint4*)(qp + d4 * 8);
                float qf[8];
                qf[0] = bu2f((unsigned short)(qv.x & 0xffff)); qf[1] = bu2f((unsigned short)(qv.x >> 16));
                qf[2] = bu2f((unsigned short)(qv.y & 0xffff)); qf[3] = bu2f((unsigned short)(qv.y >> 16));
                qf[4] = bu2f((unsigned short)(qv.z & 0xffff)); qf[5] = bu2f((unsigned short)(qv.z >> 16));
                qf[6] = bu2f((unsigned short)(qv.w & 0xffff)); qf[7] = bu2f((unsigned short)(qv.w >> 16));
#pragma unroll
                for (int j = 0; j < 4; ++j) {
                    uint4 kv = *(const uint4*)(Kb16 + (tk0 + j) * 136 + hh * 32 + d4 * 8);
                    a[j] += qf[0] * bu2f((unsigned short)(kv.x & 0xffff));
                    a[j] += qf[1] * bu2f((unsigned short)(kv.x >> 16));
                    a[j] += qf[2] * bu2f((unsigned short)(kv.y & 0xffff));
                    a[j] += qf[3] * bu2f((unsigned short)(kv.y >> 16));
                    a[j] += qf[4] * bu2f((unsigned short)(kv.z & 0xffff));
                    a[j] += qf[5] * bu2f((unsigned short)(kv.z >> 16));
                    a[j] += qf[6] * bu2f((unsigned short)(kv.w & 0xffff));
                    a[j] += qf[7] * bu2f((unsigned short)(kv.w >> 16));
                }
            }
#pragma unroll
            for (int j = 0; j < 4; ++j)
                sb[(tk0 + j) * 64 + hh * 16 + tq] = a[j] * 0.17677669529663687f;
        }
        __syncthreads();
        if (tid < 64) {   // softmax per (hh,tq) column
            float mx = -1e30f;
#pragma unroll
            for (int u = 0; u < 16; ++u) mx = fmaxf(mx, sb[u * 64 + tid]);
            float s = 0.f;
#pragma unroll
            for (int u = 0; u < 16; ++u) { float e = __expf(sb[u * 64 + tid] - mx); sb[u * 64 + tid] = e; s += e; }
            float inv = 1.f / s;
#pragma unroll
            for (int u = 0; u < 16; ++u) sb[u * 64 + tid] *= inv;
        }
        __syncthreads();
        // ---- O = P @ V (fp32, bf16 V) -> xb16 ----
        {
            int o = tid & 127, r0p = (tid >> 7) * 8, hh = o >> 5;
            float accp[8] = {0, 0, 0, 0, 0, 0, 0, 0};
            for (int u = 0; u < 16; ++u) {
                float vv = bu2f(Vb16[u * 136 + o]);
                const float* pp = sb + u * 64 + hh * 16 + r0p;
#pragma unroll
                for (int r = 0; r < 8; ++r) accp[r] += pp[r] * vv;
            }
#pragma unroll
            for (int r = 0; r < 8; ++r)
                xb16[(r0p + r) * 136 + o] = f2b(accp[r]);
        }
        __syncthreads();
        // ---- Wo via MFMA: wave w does nt = 2w, 2w+1; one batch of 8 loads ----
        {
            bf16x8 af[4];
#pragma unroll
            for (int ks = 0; ks < 4; ++ks)
                af[ks] = *(const bf16x8*)(xb16 + mrow * 136 + ks * 32 + quad * 8);
            const unsigned short* Ws = Wl + 49152;
            bf16x8 wb[8];
#pragma unroll
            for (int u = 0; u < 2; ++u) {
                int nt = w * 2 + u;
#pragma unroll
                for (int ks = 0; ks < 4; ++ks)
                    wb[u * 4 + ks] = *(const bf16x8*)(Ws + (size_t)((nt * 4 + ks) * 64 + lane) * 8);
            }
            f32x4 acc[2];
            acc[0] = (f32x4){0.f, 0.f, 0.f, 0.f};
            acc[1] = (f32x4){0.f, 0.f, 0.f, 0.f};
#pragma unroll
            for (int u = 0; u < 2; ++u)
#pragma unroll
                for (int ks = 0; ks < 4; ++ks)
                    acc[u] = __builtin_amdgcn_mfma_f32_16x16x32_bf16(af[ks], wb[u * 4 + ks], acc[u], 0, 0, 0);
#pragma unroll
            for (int u = 0; u < 2; ++u) {
                int col = (w * 2 + u) * 16 + mrow;
                float bb = bo[l * 128 + col];
#pragma unroll
                for (int r = 0; r < 4; ++r)
                    xs[(quad * 4 + r) * 128 + col] += acc[u][r] + bb;
            }
        }
        __syncthreads();
        ln256(xs, ln1s + l * 128, ln1b + l * 128);
        // ---- xs -> xb16 (post-LN1) ----
        {
            const float* xp = xs + crow * 128 + ccb;
            unsigned v[4];
#pragma unroll
            for (int j = 0; j < 4; ++j)
                v[j] = (unsigned)f2b(xp[2 * j]) | ((unsigned)f2b(xp[2 * j + 1]) << 16);
            *(uint4*)(xb16 + crow * 136 + ccb) = make_uint4(v[0], v[1], v[2], v[3]);
        }
        __syncthreads();
        // ---- FF1 via MFMA: wave w does nt = 8w..8w+7, batched; relu -> hid16 ----
        {
            bf16x8 af[4];
#pragma unroll
            for (int ks = 0; ks < 4; ++ks)
                af[ks] = *(const bf16x8*)(xb16 + mrow * 136 + ks * 32 + quad * 8);
            f32x4 acc[8];
#pragma unroll
            for (int i = 0; i < 8; ++i) acc[i] = (f32x4){0.f, 0.f, 0.f, 0.f};
            const unsigned short* Ws = Wl + 65536;
#pragma unroll
            for (int ib = 0; ib < 4; ++ib) {
                bf16x8 wb[8];
#pragma unroll
                for (int u = 0; u < 2; ++u) {
                    int nt = w * 8 + ib * 2 + u;
#pragma unroll
                    for (int ks = 0; ks < 4; ++ks)
                        wb[u * 4 + ks] = *(const bf16x8*)(Ws + (size_t)((nt * 4 + ks) * 64 + lane) * 8);
                }
#pragma unroll
                for (int u = 0; u < 2; ++u)
#pragma unroll
                    for (int ks = 0; ks < 4; ++ks)
                        acc[ib * 2 + u] = __builtin_amdgcn_mfma_f32_16x16x32_bf16(af[ks], wb[u * 4 + ks], acc[ib * 2 + u], 0, 0, 0);
            }
#pragma unroll
            for (int i = 0; i < 8; ++i) {
                int col = (w * 8 + i) * 16 + mrow;
                float bb = bff1[l * 512 + col];
#pragma unroll
                for (int r = 0; r < 4; ++r) {
                    float v = fmaxf(acc[i][r] + bb, 0.f);
                    hid16[(quad * 4 + r) * 520 + col] = f2b(v);
                }
            }
        }
        __syncthreads();
        // ---- FF2 via MFMA: 2 nt x 16 ks per wave, batched 4 ks at a time ----
        {
            f32x4 a0 = (f32x4){0.f, 0.f, 0.f, 0.f};
            f32x4 a1 = (f32x4){0.f, 0.f, 0.f, 0.f};
            const unsigned short* Ws = Wl + 131072;
            int nt0 = w * 2, nt1 = w * 2 + 1;
#pragma unroll
            for (int kb = 0; kb < 4; ++kb) {
                bf16x8 afb[4], w0[4], w1[4];
#pragma unroll
                for (int kk = 0; kk < 4; ++kk) {
                    int ks = kb * 4 + kk;
                    afb[kk] = *(const bf16x8*)(hid16 + mrow * 520 + ks * 32 + quad * 8);
                    w0[kk] = *(const bf16x8*)(Ws + (size_t)((nt0 * 16 + ks) * 64 + lane) * 8);
                    w1[kk] = *(const bf16x8*)(Ws + (size_t)((nt1 * 16 + ks) * 64 + lane) * 8);
                }
#pragma unroll
                for (int kk = 0; kk < 4; ++kk) {
                    a0 = __builtin_amdgcn_mfma_f32_16x16x32_bf16(afb[kk], w0[kk], a0, 0, 0, 0);
                    a1 = __builtin_amdgcn_mfma_f32_16x16x32_bf16(afb[kk], w1[kk], a1, 0, 0, 0);
                }
            }
            int col0 = nt0 * 16 + mrow, col1 = nt1 * 16 + mrow;
            float bb0 = bff2[l * 128 + col0], bb1 = bff2[l * 128 + col1];
#pragma unroll
            for (int r = 0; r < 4; ++r) {
                xs[(quad * 4 + r) * 128 + col0] += a0[r] + bb0;
                xs[(quad * 4 + r) * 128 + col1] += a1[r] + bb1;
            }
        }
        __syncthreads();
        ln256(xs, ln2s + l * 128, ln2b + l * 128);
    }
    for (int idx = tid; idx < 2048; idx += 256)
        out[(size_t)m * 2048 + idx] = xs[idx];
}

extern "C" void kernel_launch(void* const* d_in, const int* in_sizes, int n_in,
                              void* d_out, int out_size, void* d_ws, size_t ws_size,
                              hipStream_t stream) {
    (void)in_sizes; (void)n_in; (void)out_size; (void)ws_size;
    const int*   ego  = (const int*)d_in[0];
    const float* pos  = (const float*)d_in[1];
    const float* adj  = (const float*)d_in[2];
    const float* g1W  = (const float*)d_in[3];
    const float* g1as = (const float*)d_in[4];
    const float* g1ad = (const float*)d_in[5];
    const float* g1b  = (const float*)d_in[6];
    const float* gW   = (const float*)d_in[7];
    const float* gas  = (const float*)d_in[8];
    const float* gad  = (const float*)d_in[9];
    const float* gb   = (const float*)d_in[10];
    const float* Wqkv = (const float*)d_in[11];
    const float* bqkv = (const float*)d_in[12];
    const float* Wo   = (const float*)d_in[13];
    const float* bo   = (const float*)d_in[14];
    const float* l1s  = (const float*)d_in[15];
    const float* l1b  = (const float*)d_in[16];
    const float* l2s  = (const float*)d_in[17];
    const float* l2b  = (const float*)d_in[18];
    const float* Wff1 = (const float*)d_in[19];
    const float* bff1 = (const float*)d_in[20];
    const float* Wff2 = (const float*)d_in[21];
    const float* bff2 = (const float*)d_in[22];

    unsigned short* x0  = (unsigned short*)d_ws;       // 2,097,152 sh (4 MB)
    unsigned short* x1  = x0 + 2097152;                // 4 MB
    unsigned short* h16 = x1 + 2097152;                // 8,388,608 sh (16 MB)
    float* ssb = (float*)(h16 + 8388608);              // 65,536 f
    float* sdb = ssb + 65536;                          // 65,536 f
    float* mfl = sdb + 65536;                          // 16,384 f
    int*   cnt = (int*)(mfl + 16384);                  // 16,384 i
    int*   nbr = cnt + 16384;                          // 1,048,576 i
    unsigned short* Wb16 = (unsigned short*)(nbr + 1048576);  // 1,310,720 sh (~2.6 MB)
    unsigned short* Wg16 = Wb16 + 983040;              // GAT weight frags

    k_prep<<<640, 256, 0, stream>>>(Wqkv, Wo, Wff1, Wff2, gW, Wb16);
    k_init<<<64, 256, 0, stream>>>(ego, mfl, cnt);
    k_edges<<<1024, 256, 0, stream>>>(adj, mfl, cnt, nbr);

    // GAT layer 1 (F=2), projection + ss/sd fused
    k_gat1<<<NROWS, 128, 0, stream>>>(pos, g1W, g1as, g1ad, h16, ssb, sdb);
    k_agg<<<4096, 256, 0, stream>>>(h16, ssb, sdb, cnt, nbr, mfl, g1b, x0);

    unsigned short* xin = x0; unsigned short* xout = x1;
    for (int L = 0; L < 5; ++L) {
        k_gat_h<<<512, 256, 0, stream>>>(xin, Wg16 + (size_t)L * 65536,
                                         gas + L * 512, gad + L * 512, h16, ssb, sdb);
        k_agg<<<4096, 256, 0, stream>>>(h16, ssb, sdb, cnt, nbr, mfl, gb + L * 128, xout);
        unsigned short* tmp = xin; xin = xout; xout = tmp;
    }

    k_tf<<<MM, 256, 0, stream>>>(xin, Wb16, bqkv, bo, l1s, l1b, l2s, l2b,
                                 bff1, bff2, (float*)d_out);
}